// Round 4
// baseline (153.615 us; speedup 1.0000x reference)
//
#include <hip/hip_runtime.h>

#define NPF 16
#define NH 8
#define NV 16
#define NN 900
#define ND 256
#define NB 4
#define NM (NN * NN)          // 810000
#define TOTAL (NB * NM)       // 3240000

// ============================ Kernel A: imap ============================
// One block per (b,n). Computes x[b,n,m] = 1 - imap_norm and stores to ws.
__global__ __launch_bounds__(256) void hough_imap(
    const float* __restrict__ queries,
    const float* __restrict__ cur_ref,
    const float* __restrict__ vote_w,
    const float* __restrict__ vote_b,
    float* __restrict__ xbuf)
{
    __shared__ __align__(16) float qs[ND];
    __shared__ float part[256];
    __shared__ float vp[NV * 2];
    __shared__ float s2i[NV];
    __shared__ __align__(16) float4 sCoef[NV];
    __shared__ float red[4];
    __shared__ float s_inv;

    const int tid = threadIdx.x;
    const int bn  = blockIdx.x;
    const int b   = bn / NN;
    const int n   = bn - b * NN;

    qs[tid] = queries[(size_t)bn * ND + tid];
    __syncthreads();

    // votes: 32 outputs, 8 threads each over D=256
    {
        const int o     = tid & 31;
        const int chunk = tid >> 5;
        const float4* wv = (const float4*)(vote_w + o * ND + chunk * 32);
        const float4* qv = (const float4*)(qs + chunk * 32);
        float p = 0.f;
#pragma unroll
        for (int j = 0; j < 8; j++) {
            float4 w4 = wv[j];
            float4 q4 = qv[j];
            p += w4.x * q4.x + w4.y * q4.y + w4.z * q4.z + w4.w * q4.w;
        }
        part[tid] = p;
    }
    __syncthreads();

    if (tid < 32) {
        float s = vote_b[tid];
#pragma unroll
        for (int c = 0; c < 8; c++) s += part[c * 32 + tid];
        vp[tid] = s + cur_ref[((size_t)b * NN + n) * 4 + (tid & 1)];
    } else if (tid >= 64 && tid < 64 + NV) {
        // sigma quirk: sigma_flat[b, i] = sigma[b, i % N], i = n*V + v
        int v = tid - 64;
        int j = (n * NV + v) % NN;
        float c2 = cur_ref[((size_t)b * NN + j) * 4 + 2];
        float c3 = cur_ref[((size_t)b * NN + j) * 4 + 3];
        float sg = (c2 + c3) * 0.25f;   // mean(c2,c3)/2
        s2i[v] = 0.5f / (sg * sg);
    }
    __syncthreads();

    // fold: exponent(m,v) = min(C0 + Ax*cx + Ay*cy + nS*cc, 0)
    if (tid < NV) {
        float x  = vp[2 * tid];
        float y  = vp[2 * tid + 1];
        float s2 = s2i[tid];
        sCoef[tid] = make_float4(2.f * s2 * x, 2.f * s2 * y,
                                 -s2 * (x * x + y * y), -s2);
    }
    __syncthreads();

    float acc[4] = {0.f, 0.f, 0.f, 0.f};
    const float4* cr4 = (const float4*)cur_ref + (size_t)b * NN;

#pragma unroll 1
    for (int c = 0; c < 2; c++) {       // two chunks of 8 votes, ~32 coeff regs
        float ax[8], ay[8], c0[8], ns[8];
#pragma unroll
        for (int v = 0; v < 8; v++) {
            float4 f = sCoef[c * 8 + v];   // LDS broadcast
            ax[v] = f.x; ay[v] = f.y; c0[v] = f.z; ns[v] = f.w;
        }
#pragma unroll
        for (int i = 0; i < 4; i++) {
            int m = tid + 256 * i;
            if (m < NN) {
                float4 cr = cr4[m];
                float cx = cr.x, cy = cr.y;
                float cc = cx * cx + cy * cy;
                float a = 0.f;
#pragma unroll
                for (int v = 0; v < 8; v++) {
                    float t = fmaf(ax[v], cx, c0[v]);
                    t = fmaf(ay[v], cy, t);
                    t = fmaf(ns[v], cc, t);
                    a += __expf(fminf(t, 0.f));
                }
                acc[i] += a;
            }
        }
    }

    // block reduce (acc >= 0, |.| redundant)
    float lsum = acc[0] + acc[1] + acc[2] + acc[3];
#pragma unroll
    for (int off = 32; off > 0; off >>= 1) lsum += __shfl_down(lsum, off, 64);
    if ((tid & 63) == 0) red[tid >> 6] = lsum;
    __syncthreads();
    if (tid == 0)
        s_inv = 1.0f / fmaxf(red[0] + red[1] + red[2] + red[3], 1e-12f);
    __syncthreads();
    const float inv = s_inv;

    float* xr = xbuf + (size_t)bn * NN;
#pragma unroll
    for (int i = 0; i < 4; i++) {
        int m = tid + 256 * i;
        if (m < NN) xr[m] = 1.0f - acc[i] * inv;
    }
}

// ========================= Kernel B: epilogue =========================
// One thread per (b,n,m): 16 trig once, 8 heads x 16 FMA, 8 coalesced stores.
__global__ __launch_bounds__(256) void hough_epi(
    const float* __restrict__ xbuf,
    const float* __restrict__ proj_w,
    const float* __restrict__ proj_b,
    float* __restrict__ out)
{
    __shared__ __align__(16) float4 sW[NH * 4];   // 128 floats
    __shared__ float sB[NH];

    const int tid = threadIdx.x;
    if (tid < NH * 4) sW[tid] = ((const float4*)proj_w)[tid];
    if (tid < NH) sB[tid] = proj_b[tid];
    __syncthreads();

    const int id = blockIdx.x * 256 + tid;
    if (id >= TOTAL) return;

    const float x = xbuf[id];

    // 100 / 10000^(k/8)
    const float invt[8] = {100.0f, 31.622776601683793f, 10.0f, 3.1622776601683795f,
                           1.0f, 0.31622776601683794f, 0.1f, 0.031622776601683791f};
    float sk[8], ck[8];
#pragma unroll
    for (int k = 0; k < 8; k++) {
        float a = x * invt[k];
        sk[k] = __sinf(a);
        ck[k] = __cosf(a);
    }

    // id = (b*NN + n)*NN + m ; out index = b*NH*NM + h*NM + (n*NN + m)
    const int b = id / NM;
    const int r = id - b * NM;
    float* op = out + (size_t)b * NH * NM + r;

#pragma unroll
    for (int h = 0; h < NH; h++) {
        const float4 w0 = sW[h * 4 + 0];   // broadcast ds_read_b128
        const float4 w1 = sW[h * 4 + 1];
        const float4 w2 = sW[h * 4 + 2];
        const float4 w3 = sW[h * 4 + 3];
        float o = sB[h];
        o = fmaf(w0.x, sk[0], o); o = fmaf(w0.y, ck[0], o);
        o = fmaf(w0.z, sk[1], o); o = fmaf(w0.w, ck[1], o);
        o = fmaf(w1.x, sk[2], o); o = fmaf(w1.y, ck[2], o);
        o = fmaf(w1.z, sk[3], o); o = fmaf(w1.w, ck[3], o);
        o = fmaf(w2.x, sk[4], o); o = fmaf(w2.y, ck[4], o);
        o = fmaf(w2.z, sk[5], o); o = fmaf(w2.w, ck[5], o);
        o = fmaf(w3.x, sk[6], o); o = fmaf(w3.y, ck[6], o);
        o = fmaf(w3.z, sk[7], o); o = fmaf(w3.w, ck[7], o);
        op[(size_t)h * NM] = fmaxf(o, 0.f);
    }
}

extern "C" void kernel_launch(void* const* d_in, const int* in_sizes, int n_in,
                              void* d_out, int out_size, void* d_ws, size_t ws_size,
                              hipStream_t stream) {
    const float* queries = (const float*)d_in[0];
    const float* cur_ref = (const float*)d_in[1];
    // d_in[2] = prev_ref_points: unused by the reference
    const float* vote_w  = (const float*)d_in[3];
    const float* vote_b  = (const float*)d_in[4];
    const float* proj_w  = (const float*)d_in[5];
    const float* proj_b  = (const float*)d_in[6];
    float* out  = (float*)d_out;
    float* xbuf = (float*)d_ws;   // TOTAL floats = 12.96 MB

    hough_imap<<<NB * NN, 256, 0, stream>>>(queries, cur_ref, vote_w, vote_b, xbuf);
    hough_epi<<<(TOTAL + 255) / 256, 256, 0, stream>>>(xbuf, proj_w, proj_b, out);
}

// Round 5
// 153.573 us; speedup vs baseline: 1.0003x; 1.0003x over previous
//
#include <hip/hip_runtime.h>

#define NPF 16
#define NH 8
#define NV 16
#define NN 900
#define ND 256
#define NB 4
#define NM (NN * NN)          // 810000
#define TOTAL (NB * NM)       // 3240000
#define EPB 1024              // elements per epilogue block (4 per thread)

// ============================ Kernel A: imap ============================
// One block per (b,n). Computes x[b,n,m] = 1 - imap_norm and stores to ws.
__global__ __launch_bounds__(256) void hough_imap(
    const float* __restrict__ queries,
    const float* __restrict__ cur_ref,
    const float* __restrict__ vote_w,
    const float* __restrict__ vote_b,
    float* __restrict__ xbuf)
{
    __shared__ __align__(16) float qs[ND];
    __shared__ float part[256];
    __shared__ float vp[NV * 2];
    __shared__ float s2i[NV];
    __shared__ __align__(16) float4 sCoef[NV];
    __shared__ float red[4];
    __shared__ float s_inv;

    const int tid = threadIdx.x;
    const int bn  = blockIdx.x;
    const int b   = bn / NN;
    const int n   = bn - b * NN;

    qs[tid] = queries[(size_t)bn * ND + tid];
    __syncthreads();

    // votes: 32 outputs, 8 threads each over D=256
    {
        const int o     = tid & 31;
        const int chunk = tid >> 5;
        const float4* wv = (const float4*)(vote_w + o * ND + chunk * 32);
        const float4* qv = (const float4*)(qs + chunk * 32);
        float p = 0.f;
#pragma unroll
        for (int j = 0; j < 8; j++) {
            float4 w4 = wv[j];
            float4 q4 = qv[j];
            p += w4.x * q4.x + w4.y * q4.y + w4.z * q4.z + w4.w * q4.w;
        }
        part[tid] = p;
    }
    __syncthreads();

    if (tid < 32) {
        float s = vote_b[tid];
#pragma unroll
        for (int c = 0; c < 8; c++) s += part[c * 32 + tid];
        vp[tid] = s + cur_ref[((size_t)b * NN + n) * 4 + (tid & 1)];
    } else if (tid >= 64 && tid < 64 + NV) {
        // sigma quirk: sigma_flat[b, i] = sigma[b, i % N], i = n*V + v
        int v = tid - 64;
        int j = (n * NV + v) % NN;
        float c2 = cur_ref[((size_t)b * NN + j) * 4 + 2];
        float c3 = cur_ref[((size_t)b * NN + j) * 4 + 3];
        float sg = (c2 + c3) * 0.25f;   // mean(c2,c3)/2
        s2i[v] = 0.5f / (sg * sg);
    }
    __syncthreads();

    // fold: exponent(m,v) = min(C0 + Ax*cx + Ay*cy + nS*cc, 0)
    if (tid < NV) {
        float x  = vp[2 * tid];
        float y  = vp[2 * tid + 1];
        float s2 = s2i[tid];
        sCoef[tid] = make_float4(2.f * s2 * x, 2.f * s2 * y,
                                 -s2 * (x * x + y * y), -s2);
    }
    __syncthreads();

    float acc[4] = {0.f, 0.f, 0.f, 0.f};
    const float4* cr4 = (const float4*)cur_ref + (size_t)b * NN;

#pragma unroll 1
    for (int c = 0; c < 2; c++) {       // two chunks of 8 votes
        float ax[8], ay[8], c0[8], ns[8];
#pragma unroll
        for (int v = 0; v < 8; v++) {
            float4 f = sCoef[c * 8 + v];   // LDS broadcast, 16 total
            ax[v] = f.x; ay[v] = f.y; c0[v] = f.z; ns[v] = f.w;
        }
#pragma unroll
        for (int i = 0; i < 4; i++) {
            int m = tid + 256 * i;
            if (m < NN) {
                float4 cr = cr4[m];
                float cx = cr.x, cy = cr.y;
                float cc = cx * cx + cy * cy;
                float a = 0.f;
#pragma unroll
                for (int v = 0; v < 8; v++) {
                    float t = fmaf(ax[v], cx, c0[v]);
                    t = fmaf(ay[v], cy, t);
                    t = fmaf(ns[v], cc, t);
                    a += __expf(fminf(t, 0.f));
                }
                acc[i] += a;
            }
        }
    }

    // block reduce (acc >= 0, |.| redundant)
    float lsum = acc[0] + acc[1] + acc[2] + acc[3];
#pragma unroll
    for (int off = 32; off > 0; off >>= 1) lsum += __shfl_down(lsum, off, 64);
    if ((tid & 63) == 0) red[tid >> 6] = lsum;
    __syncthreads();
    if (tid == 0)
        s_inv = 1.0f / fmaxf(red[0] + red[1] + red[2] + red[3], 1e-12f);
    __syncthreads();
    const float inv = s_inv;

    float* xr = xbuf + (size_t)bn * NN;
#pragma unroll
    for (int i = 0; i < 4; i++) {
        int m = tid + 256 * i;
        if (m < NN) xr[m] = 1.0f - acc[i] * inv;
    }
}

// ========================= Kernel B: epilogue =========================
// 4 elements per thread; trig once; weights in SGPRs (readfirstlane-pinned);
// zero LDS in the hot path.
__device__ __forceinline__ float uload(const float* p) {
    return __int_as_float(__builtin_amdgcn_readfirstlane(__float_as_int(*p)));
}

__global__ __launch_bounds__(256)
__attribute__((amdgpu_waves_per_eu(4, 4)))
void hough_epi(
    const float* __restrict__ xbuf,
    const float* __restrict__ proj_w,
    const float* __restrict__ proj_b,
    float* __restrict__ out)
{
    const int tid  = threadIdx.x;
    const int base = blockIdx.x * EPB + tid;

    // 100 / 10000^(k/8)
    const float invt[8] = {100.0f, 31.622776601683793f, 10.0f, 3.1622776601683795f,
                           1.0f, 0.31622776601683794f, 0.1f, 0.031622776601683791f};

    float sk[4][8], ck[4][8];
    float* op[4];
    bool ok[4];
#pragma unroll
    for (int i = 0; i < 4; i++) {
        int id = base + 256 * i;
        ok[i] = (id < TOTAL);
        float x = ok[i] ? xbuf[id] : 0.f;
#pragma unroll
        for (int k = 0; k < 8; k++) {
            float a = x * invt[k];
            sk[i][k] = __sinf(a);
            ck[i][k] = __cosf(a);
        }
        unsigned int b = (unsigned int)id / (unsigned int)NM;   // magic-mul
        unsigned int r = (unsigned int)id - b * (unsigned int)NM;
        op[i] = out + (size_t)b * NH * NM + r;
    }

#pragma unroll 1
    for (int pass = 0; pass < 4; pass++) {       // 2 heads per pass
        float w[32];
#pragma unroll
        for (int k = 0; k < 32; k++) w[k] = uload(proj_w + pass * 32 + k);
        const float b0 = uload(proj_b + pass * 2 + 0);
        const float b1 = uload(proj_b + pass * 2 + 1);

#pragma unroll
        for (int i = 0; i < 4; i++) {
            float o0 = b0, o1 = b1;
#pragma unroll
            for (int k = 0; k < 8; k++) {
                o0 = fmaf(w[2 * k],          sk[i][k], o0);
                o0 = fmaf(w[2 * k + 1],      ck[i][k], o0);
                o1 = fmaf(w[16 + 2 * k],     sk[i][k], o1);
                o1 = fmaf(w[16 + 2 * k + 1], ck[i][k], o1);
            }
            if (ok[i]) {
                op[i][(size_t)(pass * 2 + 0) * NM] = fmaxf(o0, 0.f);
                op[i][(size_t)(pass * 2 + 1) * NM] = fmaxf(o1, 0.f);
            }
        }
    }
}

extern "C" void kernel_launch(void* const* d_in, const int* in_sizes, int n_in,
                              void* d_out, int out_size, void* d_ws, size_t ws_size,
                              hipStream_t stream) {
    const float* queries = (const float*)d_in[0];
    const float* cur_ref = (const float*)d_in[1];
    // d_in[2] = prev_ref_points: unused by the reference
    const float* vote_w  = (const float*)d_in[3];
    const float* vote_b  = (const float*)d_in[4];
    const float* proj_w  = (const float*)d_in[5];
    const float* proj_b  = (const float*)d_in[6];
    float* out  = (float*)d_out;
    float* xbuf = (float*)d_ws;   // TOTAL floats = 12.96 MB

    hough_imap<<<NB * NN, 256, 0, stream>>>(queries, cur_ref, vote_w, vote_b, xbuf);
    hough_epi<<<(TOTAL + EPB - 1) / EPB, 256, 0, stream>>>(xbuf, proj_w, proj_b, out);
}